// Round 3
// baseline (1697.045 us; speedup 1.0000x reference)
//
#include <hip/hip_runtime.h>

// DoubleKVCache — DIAGNOSTIC ROUND: fused kernel body repeated 3x (idempotent)
// so the dispatch exceeds the harness fills' ~510 us and surfaces in the
// rocprof top-5 with its own hbm_gbps. Single-pass kernel BW = 3*1.61GB/dur.
//
// B=2, H=32, S_MAX=8192, D=128, S_NEW=in_sizes[0] (512)
// out0 = kt_cache^T w/ scatter, out1 = k_cache w/ scatter, out2 = v_cache w/ scatter

#define S_MAXC 8192
#define DC     128
#define BHC    64   // B*H
#define PROBE_REPEAT 3

typedef __attribute__((ext_vector_type(4))) float v4f;

__global__ void init_inv(int* __restrict__ inv) {
    int i = blockIdx.x * blockDim.x + threadIdx.x;
    if (i < S_MAXC) inv[i] = -1;
}

__global__ void scatter_inv(const int* __restrict__ pos, int* __restrict__ inv, int n) {
    int j = blockIdx.x * blockDim.x + threadIdx.x;
    if (j < n) inv[pos[j]] = j;
}

__global__ void __launch_bounds__(256) fused_kv(
        const v4f* __restrict__ k_val,    // [BH][S_NEW][32]
        const v4f* __restrict__ v_val,
        const v4f* __restrict__ k_cache,  // [BH][S_MAX][32]
        const v4f* __restrict__ v_cache,
        const float* __restrict__ kt_cache, // [BH][D][S_MAX]
        const int*  __restrict__ inv,
        v4f* __restrict__ out0,
        v4f* __restrict__ out1,
        v4f* __restrict__ out2,
        int s_new) {
    __shared__ __align__(16) float tile[32][132]; // [s_local][d], pad 132
    const int tid = blockIdx.x;      // 0..16383
    const int bh  = tid >> 8;        // 256 s-tiles per bh
    const int s0  = (tid & 255) << 5;
    const int t   = threadIdx.x;
    const int q   = t & 7;           // 0..7
    const int r   = t >> 3;          // 0..31

    for (int rep = 0; rep < PROBE_REPEAT; ++rep) {
        // Phase A: stage 128(d) x 32(s) kt tile into LDS (transposing).
        const float* ktb = kt_cache + (long)bh * DC * S_MAXC;
        #pragma unroll
        for (int p = 0; p < 4; ++p) {
            int d = p * 32 + r;
            v4f vld = __builtin_nontemporal_load(
                (const v4f*)(ktb + (long)d * S_MAXC + s0 + 4 * q));
            tile[4 * q + 0][d] = vld.x;
            tile[4 * q + 1][d] = vld.y;
            tile[4 * q + 2][d] = vld.z;
            tile[4 * q + 3][d] = vld.w;
        }
        __syncthreads();

        // Phase B: 8 lanes per output row s = s0 + r, 4 v4f per tensor.
        const int s = s0 + r;
        const int j = inv[s];
        const long row = (long)bh * S_MAXC + s;
        v4f* o0 = out0 + row * 32;
        v4f* o1 = out1 + row * 32;
        v4f* o2 = out2 + row * 32;
        if (j >= 0) {
            const v4f* kv = k_val + ((long)bh * s_new + j) * 32;
            const v4f* vv = v_val + ((long)bh * s_new + j) * 32;
            #pragma unroll
            for (int m = 0; m < 4; ++m) {
                int c = q + 8 * m;
                v4f kx = kv[c];
                v4f vx = vv[c];
                __builtin_nontemporal_store(kx, o0 + c);
                __builtin_nontemporal_store(kx, o1 + c);
                __builtin_nontemporal_store(vx, o2 + c);
            }
        } else {
            const v4f* kc = k_cache + row * 32;
            const v4f* vc = v_cache + row * 32;
            #pragma unroll
            for (int m = 0; m < 4; ++m) {
                int c = q + 8 * m;
                v4f kx = __builtin_nontemporal_load(kc + c);
                v4f vx = __builtin_nontemporal_load(vc + c);
                v4f tx = *(const v4f*)&tile[r][4 * c];
                __builtin_nontemporal_store(tx, o0 + c);
                __builtin_nontemporal_store(kx, o1 + c);
                __builtin_nontemporal_store(vx, o2 + c);
            }
        }
        __syncthreads();                 // LDS reuse safety before next rep
        asm volatile("" ::: "memory");   // force real reloads each rep
    }
}

extern "C" void kernel_launch(void* const* d_in, const int* in_sizes, int n_in,
                              void* d_out, int out_size, void* d_ws, size_t ws_size,
                              hipStream_t stream) {
    const int*   input_pos = (const int*)  d_in[0];
    const float* k_val     = (const float*)d_in[1];
    const float* v_val     = (const float*)d_in[2];
    const float* k_cache   = (const float*)d_in[3];
    const float* kt_cache  = (const float*)d_in[4];
    const float* v_cache   = (const float*)d_in[5];
    const int s_new = in_sizes[0];

    const long per_out = (long)BHC * S_MAXC * DC;   // 67,108,864 floats
    float* out0 = (float*)d_out;                    // kt^T
    float* out1 = out0 + per_out;                   // k
    float* out2 = out1 + per_out;                   // v

    int* inv = (int*)d_ws;  // 8192 ints; d_ws re-poisoned each call, rebuild

    init_inv<<<S_MAXC / 256, 256, 0, stream>>>(inv);
    scatter_inv<<<(s_new + 255) / 256, 256, 0, stream>>>(input_pos, inv, s_new);

    const int n_tiles = BHC * (S_MAXC / 32);        // 16384 blocks
    fused_kv<<<n_tiles, 256, 0, stream>>>(
        (const v4f*)k_val, (const v4f*)v_val,
        (const v4f*)k_cache, (const v4f*)v_cache,
        kt_cache, inv,
        (v4f*)out0, (v4f*)out1, (v4f*)out2, s_new);
}

// Round 4
// 1279.047 us; speedup vs baseline: 1.3268x; 1.3268x over previous
//
#include <hip/hip_runtime.h>

// DoubleKVCache: B=2, H=32, S_MAX=8192, D=128, S_NEW=in_sizes[0] (512)
// out0 = kt_cache^T w/ scatter, out1 = k_cache w/ scatter, out2 = v_cache w/ scatter
// R4: fused single-pass; 8 s-tiles per block with double-buffered LDS
// (1 barrier/tile, prefetch overlaps stores); swizzled LDS layout
// (chunk' = (d>>2 + sl>>3) & 31) -> phase-A ds_write conflict-free while
// phase-B ds_read_b128 stays 16B-aligned at its structural minimum.

#define S_MAXC 8192
#define DC     128
#define BHC    64
#define TPB    8                         // s-tiles per block
#define NBLK   ((BHC * (S_MAXC / 32)) / TPB)   // 2048 blocks

typedef __attribute__((ext_vector_type(4))) float v4f;

__global__ void init_inv(int* __restrict__ inv) {
    int i = blockIdx.x * blockDim.x + threadIdx.x;
    if (i < S_MAXC) inv[i] = -1;
}

__global__ void scatter_inv(const int* __restrict__ pos, int* __restrict__ inv, int n) {
    int j = blockIdx.x * blockDim.x + threadIdx.x;
    if (j < n) inv[pos[j]] = j;
}

__device__ __forceinline__ void stage_tile(
        const float* __restrict__ ktb, int s0, int q, int r, float* __restrict__ tb) {
    #pragma unroll
    for (int p = 0; p < 4; ++p) {
        int d = p * 32 + r;                      // r: 0..31 -> d covers 0..127
        v4f vld = __builtin_nontemporal_load(
            (const v4f*)(ktb + (long)d * S_MAXC + s0 + 4 * q));
        int c = d >> 2, w = d & 3;
        #pragma unroll
        for (int u = 0; u < 4; ++u) {
            int sl = 4 * q + u;
            // swizzled chunk: conflict-free banks across the wave
            tb[sl * 128 + (((c + (sl >> 3)) & 31) << 2) + w] = ((const float*)&vld)[u];
        }
    }
}

__global__ void __launch_bounds__(256) fused_kv(
        const v4f* __restrict__ k_val,      // [BH][S_NEW][32]
        const v4f* __restrict__ v_val,
        const v4f* __restrict__ k_cache,    // [BH][S_MAX][32]
        const v4f* __restrict__ v_cache,
        const float* __restrict__ kt_cache, // [BH][D][S_MAX]
        const int*  __restrict__ inv,
        v4f* __restrict__ out0,
        v4f* __restrict__ out1,
        v4f* __restrict__ out2,
        int s_new) {
    __shared__ __align__(16) float tile[2][32 * 128];   // 2 x 16 KiB, no pad (swizzled)
    const int t = threadIdx.x;
    const int q = t & 7;     // 0..7
    const int r = t >> 3;    // 0..31
    const int tbase = blockIdx.x * TPB;      // 8 consecutive s-tiles, same bh
    const int bh = tbase >> 8;
    const float* ktb = kt_cache + (long)bh * DC * S_MAXC;

    // Prologue: stage tile 0 into buffer 0
    stage_tile(ktb, (tbase & 255) << 5, q, r, &tile[0][0]);
    __syncthreads();

    for (int it = 0; it < TPB; ++it) {
        const int s0 = ((tbase + it) & 255) << 5;

        // Prefetch next tile into the other buffer (loads overlap phase-B stores)
        if (it + 1 < TPB)
            stage_tile(ktb, s0 + 32, q, r, &tile[(it + 1) & 1][0]);

        // Phase B: 8 lanes per output row s = s0 + r, 4 v4f per tensor
        const float* tb = &tile[it & 1][0];
        const int sl = r;
        const int s  = s0 + sl;
        const int j  = inv[s];
        const long row = (long)bh * S_MAXC + s;
        v4f* o0 = out0 + row * 32;
        v4f* o1 = out1 + row * 32;
        v4f* o2 = out2 + row * 32;
        if (j >= 0) {
            const v4f* kv = k_val + ((long)bh * s_new + j) * 32;
            const v4f* vv = v_val + ((long)bh * s_new + j) * 32;
            #pragma unroll
            for (int m = 0; m < 4; ++m) {
                int c = q + 8 * m;
                v4f kx = kv[c];
                v4f vx = vv[c];
                __builtin_nontemporal_store(kx, o0 + c);
                __builtin_nontemporal_store(kx, o1 + c);
                __builtin_nontemporal_store(vx, o2 + c);
            }
        } else {
            const v4f* kc = k_cache + row * 32;
            const v4f* vc = v_cache + row * 32;
            #pragma unroll
            for (int m = 0; m < 4; ++m) {
                int c = q + 8 * m;
                int pc = (c + (sl >> 3)) & 31;
                v4f kx = __builtin_nontemporal_load(kc + c);
                v4f vx = __builtin_nontemporal_load(vc + c);
                v4f tx = *(const v4f*)&tb[sl * 128 + (pc << 2)];
                __builtin_nontemporal_store(tx, o0 + c);
                __builtin_nontemporal_store(kx, o1 + c);
                __builtin_nontemporal_store(vx, o2 + c);
            }
        }
        __syncthreads();   // one barrier per tile (protects both LDS buffers)
    }
}

extern "C" void kernel_launch(void* const* d_in, const int* in_sizes, int n_in,
                              void* d_out, int out_size, void* d_ws, size_t ws_size,
                              hipStream_t stream) {
    const int*   input_pos = (const int*)  d_in[0];
    const float* k_val     = (const float*)d_in[1];
    const float* v_val     = (const float*)d_in[2];
    const float* k_cache   = (const float*)d_in[3];
    const float* kt_cache  = (const float*)d_in[4];
    const float* v_cache   = (const float*)d_in[5];
    const int s_new = in_sizes[0];

    const long per_out = (long)BHC * S_MAXC * DC;   // 67,108,864 floats
    float* out0 = (float*)d_out;                    // kt^T
    float* out1 = out0 + per_out;                   // k
    float* out2 = out1 + per_out;                   // v

    int* inv = (int*)d_ws;  // 8192 ints; d_ws re-poisoned each call, rebuild

    init_inv<<<S_MAXC / 256, 256, 0, stream>>>(inv);
    scatter_inv<<<(s_new + 255) / 256, 256, 0, stream>>>(input_pos, inv, s_new);

    fused_kv<<<NBLK, 256, 0, stream>>>(
        (const v4f*)k_val, (const v4f*)v_val,
        (const v4f*)k_cache, (const v4f*)v_cache,
        kt_cache, inv,
        (v4f*)out0, (v4f*)out1, (v4f*)out2, s_new);
}

// Round 5
// 1257.405 us; speedup vs baseline: 1.3496x; 1.0172x over previous
//
#include <hip/hip_runtime.h>

// DoubleKVCache: B=2, H=32, S_MAX=8192, D=128, S_NEW=in_sizes[0] (512)
// out0 = kt_cache^T w/ scatter, out1 = k_cache w/ scatter, out2 = v_cache w/ scatter
// R5: R2's single-tile-per-block fused structure (best so far) + verified
// conflict-free LDS swizzle: chunk' = (c + (sl>>2)) & 31.
//   Phase-A ds_write bank = 4*((q + (r>>2)) & 7) + (r&3)  -> exactly 2 lanes/bank (free).
//   Phase-B ds_read_b128 stays at structural minimum (8 clk/wave).

#define S_MAXC 8192
#define DC     128
#define BHC    64   // B*H

typedef __attribute__((ext_vector_type(4))) float v4f;

__global__ void init_inv(int* __restrict__ inv) {
    int i = blockIdx.x * blockDim.x + threadIdx.x;
    if (i < S_MAXC) inv[i] = -1;
}

__global__ void scatter_inv(const int* __restrict__ pos, int* __restrict__ inv, int n) {
    int j = blockIdx.x * blockDim.x + threadIdx.x;
    if (j < n) inv[pos[j]] = j;
}

__global__ void __launch_bounds__(256) fused_kv(
        const v4f* __restrict__ k_val,      // [BH][S_NEW][32]
        const v4f* __restrict__ v_val,
        const v4f* __restrict__ k_cache,    // [BH][S_MAX][32]
        const v4f* __restrict__ v_cache,
        const float* __restrict__ kt_cache, // [BH][D][S_MAX]
        const int*  __restrict__ inv,
        v4f* __restrict__ out0,
        v4f* __restrict__ out1,
        v4f* __restrict__ out2,
        int s_new) {
    __shared__ __align__(16) float tile[32 * 128];   // 16 KiB, swizzled (no pad)
    const int tid = blockIdx.x;      // 0..16383
    const int bh  = tid >> 8;        // 256 s-tiles per bh
    const int s0  = (tid & 255) << 5;
    const int t   = threadIdx.x;
    const int q   = t & 7;           // 0..7
    const int r   = t >> 3;          // 0..31

    // Phase A: stage 128(d) x 32(s) kt tile into LDS (transposing).
    // Lane group of 8 reads one d-row as a v4f along s (128B segments).
    // Store column d of row sl at swizzled chunk (d>>2 + sl>>2) & 31.
    // Here sl = 4q+u so sl>>2 == q.
    const float* ktb = kt_cache + (long)bh * DC * S_MAXC;
    #pragma unroll
    for (int p = 0; p < 4; ++p) {
        int d = p * 32 + r;
        v4f vld = __builtin_nontemporal_load(
            (const v4f*)(ktb + (long)d * S_MAXC + s0 + 4 * q));
        int c = d >> 2, w = d & 3;
        int cc = ((c + q) & 31) << 2;
        #pragma unroll
        for (int u = 0; u < 4; ++u)
            tile[(4 * q + u) * 128 + cc + w] = ((const float*)&vld)[u];
    }
    __syncthreads();

    // Phase B: 8 lanes per output row s = s0 + r, 4 v4f per tensor.
    const int sl = r;
    const int s  = s0 + sl;
    const int j  = inv[s];
    const long row = (long)bh * S_MAXC + s;
    v4f* o0 = out0 + row * 32;
    v4f* o1 = out1 + row * 32;
    v4f* o2 = out2 + row * 32;
    if (j >= 0) {
        // Scattered row: out0 row == out1 row == k_val row; out2 = v_val row.
        const v4f* kv = k_val + ((long)bh * s_new + j) * 32;
        const v4f* vv = v_val + ((long)bh * s_new + j) * 32;
        #pragma unroll
        for (int m = 0; m < 4; ++m) {
            int c = q + 8 * m;
            v4f kx = kv[c];
            v4f vx = vv[c];
            __builtin_nontemporal_store(kx, o0 + c);
            __builtin_nontemporal_store(kx, o1 + c);
            __builtin_nontemporal_store(vx, o2 + c);
        }
    } else {
        const v4f* kc = k_cache + row * 32;
        const v4f* vc = v_cache + row * 32;
        #pragma unroll
        for (int m = 0; m < 4; ++m) {
            int c = q + 8 * m;
            int cc = ((c + (sl >> 2)) & 31) << 2;
            v4f kx = __builtin_nontemporal_load(kc + c);
            v4f vx = __builtin_nontemporal_load(vc + c);
            v4f tx = *(const v4f*)&tile[sl * 128 + cc];
            __builtin_nontemporal_store(tx, o0 + c);
            __builtin_nontemporal_store(kx, o1 + c);
            __builtin_nontemporal_store(vx, o2 + c);
        }
    }
}

extern "C" void kernel_launch(void* const* d_in, const int* in_sizes, int n_in,
                              void* d_out, int out_size, void* d_ws, size_t ws_size,
                              hipStream_t stream) {
    const int*   input_pos = (const int*)  d_in[0];
    const float* k_val     = (const float*)d_in[1];
    const float* v_val     = (const float*)d_in[2];
    const float* k_cache   = (const float*)d_in[3];
    const float* kt_cache  = (const float*)d_in[4];
    const float* v_cache   = (const float*)d_in[5];
    const int s_new = in_sizes[0];

    const long per_out = (long)BHC * S_MAXC * DC;   // 67,108,864 floats
    float* out0 = (float*)d_out;                    // kt^T
    float* out1 = out0 + per_out;                   // k
    float* out2 = out1 + per_out;                   // v

    int* inv = (int*)d_ws;  // 8192 ints; d_ws re-poisoned each call, rebuild

    init_inv<<<S_MAXC / 256, 256, 0, stream>>>(inv);
    scatter_inv<<<(s_new + 255) / 256, 256, 0, stream>>>(input_pos, inv, s_new);

    const int n_tiles = BHC * (S_MAXC / 32);        // 16384 blocks
    fused_kv<<<n_tiles, 256, 0, stream>>>(
        (const v4f*)k_val, (const v4f*)v_val,
        (const v4f*)k_cache, (const v4f*)v_cache,
        kt_cache, inv,
        (v4f*)out0, (v4f*)out1, (v4f*)out2, s_new);
}